// Round 5
// baseline (488.951 us; speedup 1.0000x reference)
//
#include <hip/hip_runtime.h>

typedef __attribute__((ext_vector_type(8))) short bfrag;
typedef __attribute__((ext_vector_type(4))) float f32x4;

__device__ __forceinline__ short f2bf(float f) {
  union { float f; unsigned u; } v; v.f = f;
  unsigned r = v.u + 0x7FFFu + ((v.u >> 16) & 1u);  // RNE
  return (short)(r >> 16);
}
__device__ __forceinline__ float bf2f(unsigned short h) {
  union { unsigned u; float f; } v; v.u = ((unsigned)h) << 16;
  return v.f;
}
__device__ __forceinline__ float gelu_exact(float g) {
  return 0.5f * g * (1.0f + erff(g * 0.70710678118654752f));
}
__device__ __forceinline__ void gld_lds16(const short* g, short* l) {
  __builtin_amdgcn_global_load_lds(
      (const __attribute__((address_space(1))) void*)g,
      (__attribute__((address_space(3))) void*)l, 16, 0, 0);
}

// ---------------- weights -> bf16: 8-deep load batches for MLP ----------------
// float4 counts: fc1 7864320 (3840 blk) | fc2 3932160 (1920) | sfc1 1048576 (512) | sfc2 524288 (256)
// 2048 float4 per block, 6528 blocks total.
__global__ __launch_bounds__(256) void k_convert_w(
    const float* __restrict__ s0, const float* __restrict__ s1,
    const float* __restrict__ s2, const float* __restrict__ s3,
    short* __restrict__ d0, short* __restrict__ d1,
    short* __restrict__ d2, short* __restrict__ d3)
{
  const int b = blockIdx.x;
  const float* s; short* d; long off;
  if (b < 3840)      { s = s0; d = d0; off = (long)b * 2048; }
  else if (b < 5760) { s = s1; d = d1; off = (long)(b - 3840) * 2048; }
  else if (b < 6272) { s = s2; d = d2; off = (long)(b - 5760) * 2048; }
  else               { s = s3; d = d3; off = (long)(b - 6272) * 2048; }
  const long base = off + threadIdx.x;
  float4 v[8];
#pragma unroll
  for (int j = 0; j < 8; j++) v[j] = ((const float4*)s)[base + j * 256];
#pragma unroll
  for (int j = 0; j < 8; j++)
    ((short4*)d)[base + j * 256] =
        make_short4(f2bf(v[j].x), f2bf(v[j].y), f2bf(v[j].z), f2bf(v[j].w));
}

// ---------------- gating (4 tokens/wave) + x->bf16 fused ----------------
__global__ __launch_bounds__(64) void k_gate(const float* __restrict__ x,
    const float* __restrict__ gw, int* __restrict__ topk_idx,
    float* __restrict__ topk_w, short* __restrict__ xbf)
{
  const int t0 = blockIdx.x * 4;
  const int lane = threadIdx.x;
  float xv[4][16];
#pragma unroll
  for (int tt = 0; tt < 4; tt++)
#pragma unroll
    for (int i = 0; i < 16; i++) {
      xv[tt][i] = x[(size_t)(t0 + tt) * 1024 + lane + 64 * i];
      xbf[(size_t)(t0 + tt) * 1024 + lane + 64 * i] = f2bf(xv[tt][i]);
    }
  float p[4][15];
#pragma unroll
  for (int e = 0; e < 15; e++) {
    float wv[16];
#pragma unroll
    for (int i = 0; i < 16; i++) wv[i] = gw[(size_t)e * 1024 + lane + 64 * i];
#pragma unroll
    for (int tt = 0; tt < 4; tt++) {
      float s = 0.f;
#pragma unroll
      for (int i = 0; i < 16; i++) s += xv[tt][i] * wv[i];
#pragma unroll
      for (int o = 32; o; o >>= 1) s += __shfl_xor(s, o, 64);
      p[tt][e] = s;
    }
  }
#pragma unroll
  for (int tt = 0; tt < 4; tt++) {
    float m = -1e30f;
#pragma unroll
    for (int e = 0; e < 15; e++) m = fmaxf(m, p[tt][e]);
    float q[15], Z = 0.f;
#pragma unroll
    for (int e = 0; e < 15; e++) { q[e] = expf(p[tt][e] - m); Z += q[e]; }
    int usedMask = 0; int bi[3]; float bv[3];
#pragma unroll
    for (int j = 0; j < 3; j++) {
      float best = -1.f; int b = 0;
#pragma unroll
      for (int e = 0; e < 15; e++) {
        bool ok = (!((usedMask >> e) & 1)) && (q[e] > best);
        if (ok) { best = q[e]; b = e; }
      }
      bi[j] = b; bv[j] = best / Z; usedMask |= 1 << b;
    }
    if (lane == tt) {
      float den = bv[0] + bv[1] + bv[2] + 1e-20f;
#pragma unroll
      for (int j = 0; j < 3; j++) {
        topk_idx[(t0 + tt) * 3 + j] = bi[j];
        topk_w[(t0 + tt) * 3 + j] = bv[j] / den;
      }
    }
  }
}

// ---------------- routing: single block, LDS atomics ----------------
__global__ __launch_bounds__(1024) void k_route(const int* __restrict__ topk_idx,
    const float* __restrict__ topk_w, int* __restrict__ cnt_g, int* __restrict__ offs_g,
    int* __restrict__ row_tok, float* __restrict__ row_wt, int* __restrict__ row_id)
{
  __shared__ int scnt[16], soffs[16], sfill[16];
  const int tid = threadIdx.x;
  if (tid < 16) { scnt[tid] = 0; sfill[tid] = 0; }
  __syncthreads();
  for (int i = tid; i < 6144; i += 1024) atomicAdd(&scnt[topk_idx[i]], 1);
  __syncthreads();
  if (tid == 0) {
    int a = 0;
    for (int e = 0; e < 15; e++) { soffs[e] = a; offs_g[e] = a; cnt_g[e] = scnt[e]; a += scnt[e]; }
  }
  __syncthreads();
  for (int i = tid; i < 6144; i += 1024) {
    int e = topk_idx[i];
    int pos = atomicAdd(&sfill[e], 1);
    int row = soffs[e] + pos;
    row_tok[row] = i / 3;
    row_wt[row] = topk_w[i];
    row_id[i] = row;
  }
}

__device__ __forceinline__ bool resolve_tile128(const int* __restrict__ cnt, int ty,
                                                int& e, int& lt) {
  int acc = 0;
#pragma unroll
  for (int i = 0; i < 15; i++) {
    int tl = (cnt[i] + 127) >> 7;
    if (ty < acc + tl) { e = i; lt = ty - acc; return true; }
    acc += tl;
  }
  return false;
}

// ============== unified fc1 (+geglu): shared blocks [0,512), expert [512,1520) ==============
__global__ __launch_bounds__(256) void k_fc1(
    const short* __restrict__ xbf,
    const short* __restrict__ wsh, const float* __restrict__ bsh, const float* __restrict__ msh,
    const short* __restrict__ wex, const float* __restrict__ bex, const float* __restrict__ mex,
    const int* __restrict__ cnt, const int* __restrict__ offs, const int* __restrict__ row_tok,
    short* __restrict__ as_buf, short* __restrict__ a_buf)
{
  __shared__ short smem[2 * 128 * 64];  // 32 KB
  short* As = smem;
  short* Bs = smem + 128 * 64;
  const int tid = threadIdx.x;
  const int bid = blockIdx.x;
  const bool sh = bid < 512;
  int f0, m0 = 0, e = 0, rowBase = 0, nrows = 128;
  if (sh) {
    f0 = (bid & 31) * 64; m0 = (bid >> 5) * 128;
  } else {
    const int b2 = bid - 512;
    int lt;
    if (!resolve_tile128(cnt, b2 >> 4, e, lt)) return;
    f0 = (b2 & 15) * 64;
    rowBase = offs[e] + lt * 128;
    nrows = cnt[e] - lt * 128; if (nrows > 128) nrows = 128;
  }
  const int lane = tid & 63, ml = lane & 15, kq = lane >> 4, mlo = lane & 7;
  const int wv = tid >> 6, wr = wv >> 1, wc = wv & 1;
  const int lrow = lane >> 3, lchk = lane & 7;
  const int Fhalf = sh ? 2048 : 1024;
  const short* wptr = sh ? wsh : (wex + (size_t)e * 2048 * 1024);
  const short* aSrc[4]; const short* bSrc[4];
#pragma unroll
  for (int t = 0; t < 4; t++) {
    const int r = wv * 32 + t * 8 + lrow;
    const int sc = (lchk ^ (r & 7)) * 8;
    if (sh) aSrc[t] = xbf + (size_t)(m0 + r) * 1024 + sc;
    else {
      const int rc = r < nrows ? r : nrows - 1;
      aSrc[t] = xbf + (size_t)row_tok[rowBase + rc] * 1024 + sc;
    }
    const int grow = (r < 64) ? (f0 + r) : (Fhalf + f0 + r - 64);
    bSrc[t] = wptr + (size_t)grow * 1024 + sc;
  }
  f32x4 acc[4][4] = {};
  for (int k0 = 0; k0 < 1024; k0 += 64) {
#pragma unroll
    for (int t = 0; t < 4; t++) gld_lds16(aSrc[t] + k0, As + (wv * 32 + t * 8) * 64);
#pragma unroll
    for (int t = 0; t < 4; t++) gld_lds16(bSrc[t] + k0, Bs + (wv * 32 + t * 8) * 64);
    __syncthreads();
#pragma unroll
    for (int kk = 0; kk < 2; kk++) {
      const int so = ((kk * 4 + kq) ^ mlo) * 8;
      bfrag af[4], bf[4];
#pragma unroll
      for (int i = 0; i < 4; i++) af[i] = *(bfrag*)&As[(wr * 64 + i * 16 + ml) * 64 + so];
#pragma unroll
      for (int j = 0; j < 4; j++) {
        const int brow = ((j >> 1) ? 64 : 0) + wc * 32 + (j & 1) * 16 + ml;
        bf[j] = *(bfrag*)&Bs[brow * 64 + so];
      }
#pragma unroll
      for (int i = 0; i < 4; i++)
#pragma unroll
        for (int j = 0; j < 4; j++)
          acc[i][j] = __builtin_amdgcn_mfma_f32_16x16x32_bf16(af[i], bf[j], acc[i][j], 0, 0, 0);
    }
    __syncthreads();
  }
  const float* bias = sh ? bsh : (bex + (size_t)e * 2048);
  const float* mult = sh ? msh : (mex + (size_t)e * 1024);
#pragma unroll
  for (int jj = 0; jj < 2; jj++) {
    const int fl = wc * 32 + jj * 16 + ml;
    const int f = f0 + fl;
    const float b1 = bias[f];
    const float b2 = bias[Fhalf + f];
    const float mv = mult[f];
#pragma unroll
    for (int i = 0; i < 4; i++)
#pragma unroll
      for (int rg = 0; rg < 4; rg++) {
        const int row = wr * 64 + i * 16 + kq * 4 + rg;
        const float h1 = acc[i][jj][rg] + b1;
        const float h2 = acc[i][jj + 2][rg] + b2;
        const short o = f2bf(gelu_exact(h2) * h1 * mv);
        if (sh) as_buf[(size_t)(m0 + row) * 2048 + f] = o;
        else if (row < nrows) a_buf[(size_t)(rowBase + row) * 1024 + f] = o;
      }
  }
}

// ============== unified fc2 + combine: shared blocks [0,128), expert [128,632) ==============
// y zero-initialized; every contribution is atomicAdd(f32).
__global__ __launch_bounds__(256) void k_fc2(
    const short* __restrict__ as_buf, const short* __restrict__ wsfc2, const float* __restrict__ s_b,
    const short* __restrict__ a_buf, const short* __restrict__ wfc2, const float* __restrict__ e_b,
    const int* __restrict__ cnt, const int* __restrict__ offs,
    const float* __restrict__ row_wt, const int* __restrict__ row_tok,
    float* __restrict__ y)
{
  __shared__ short smem[2 * 128 * 64];
  short* As = smem;
  short* Bs = smem + 128 * 64;
  const int tid = threadIdx.x;
  const int bid = blockIdx.x;
  const bool sh = bid < 128;
  int d0, m0 = 0, e = 0, rowBase = 0, nrows = 128, Klen, astr, bstr;
  const short *aBase, *bBase;
  if (sh) {
    d0 = (bid & 7) * 128; m0 = (bid >> 3) * 128;
    Klen = 2048; astr = 2048; bstr = 2048;
    aBase = as_buf; bBase = wsfc2;
  } else {
    const int b2 = bid - 128;
    int lt;
    if (!resolve_tile128(cnt, b2 >> 3, e, lt)) return;
    d0 = (b2 & 7) * 128;
    rowBase = offs[e] + lt * 128;
    nrows = cnt[e] - lt * 128; if (nrows > 128) nrows = 128;
    Klen = 1024; astr = 1024; bstr = 1024;
    aBase = a_buf + (size_t)rowBase * 1024;
    bBase = wfc2 + (size_t)e * 1024 * 1024;
  }
  const int lane = tid & 63, ml = lane & 15, kq = lane >> 4, mlo = lane & 7;
  const int wv = tid >> 6, wr = wv >> 1, wc = wv & 1;
  const int lrow = lane >> 3, lchk = lane & 7;
  const short* aSrc[4]; const short* bSrc[4];
#pragma unroll
  for (int t = 0; t < 4; t++) {
    const int r = wv * 32 + t * 8 + lrow;
    const int sc = (lchk ^ (r & 7)) * 8;
    aSrc[t] = aBase + (size_t)(sh ? (m0 + r) : r) * astr + sc;
    bSrc[t] = bBase + (size_t)(d0 + r) * bstr + sc;
  }
  f32x4 acc[4][4] = {};
  for (int k0 = 0; k0 < Klen; k0 += 64) {
#pragma unroll
    for (int t = 0; t < 4; t++) gld_lds16(aSrc[t] + k0, As + (wv * 32 + t * 8) * 64);
#pragma unroll
    for (int t = 0; t < 4; t++) gld_lds16(bSrc[t] + k0, Bs + (wv * 32 + t * 8) * 64);
    __syncthreads();
#pragma unroll
    for (int kk = 0; kk < 2; kk++) {
      const int so = ((kk * 4 + kq) ^ mlo) * 8;
      bfrag af[4], bf[4];
#pragma unroll
      for (int i = 0; i < 4; i++) af[i] = *(bfrag*)&As[(wr * 64 + i * 16 + ml) * 64 + so];
#pragma unroll
      for (int j = 0; j < 4; j++) bf[j] = *(bfrag*)&Bs[(wc * 64 + j * 16 + ml) * 64 + so];
#pragma unroll
      for (int i = 0; i < 4; i++)
#pragma unroll
        for (int j = 0; j < 4; j++)
          acc[i][j] = __builtin_amdgcn_mfma_f32_16x16x32_bf16(af[i], bf[j], acc[i][j], 0, 0, 0);
    }
    __syncthreads();
  }
#pragma unroll
  for (int j = 0; j < 4; j++) {
    const int d = d0 + wc * 64 + j * 16 + ml;
    const float bv = sh ? s_b[d] : e_b[(size_t)e * 1024 + d];
#pragma unroll
    for (int i = 0; i < 4; i++)
#pragma unroll
      for (int rg = 0; rg < 4; rg++) {
        const int row = wr * 64 + i * 16 + kq * 4 + rg;
        if (sh) {
          atomicAdd(&y[(size_t)(m0 + row) * 1024 + d], acc[i][j][rg] + bv);
        } else if (row < nrows) {
          const float wt = row_wt[rowBase + row];
          const int tok = row_tok[rowBase + row];
          atomicAdd(&y[(size_t)tok * 1024 + d], (acc[i][j][rg] + bv) * wt);
        }
      }
  }
}

extern "C" void kernel_launch(void* const* d_in, const int* in_sizes, int n_in,
                              void* d_out, int out_size, void* d_ws, size_t ws_size,
                              hipStream_t stream) {
  const float* x          = (const float*)d_in[0];
  const float* gate_w     = (const float*)d_in[1];
  const float* fc1_w      = (const float*)d_in[2];
  const float* fc1_b      = (const float*)d_in[3];
  const float* geglu_mult = (const float*)d_in[4];
  const float* fc2_w      = (const float*)d_in[5];
  const float* fc2_b      = (const float*)d_in[6];
  const float* s_fc1_w    = (const float*)d_in[7];
  const float* s_fc1_b    = (const float*)d_in[8];
  const float* s_mult     = (const float*)d_in[9];
  const float* s_fc2_w    = (const float*)d_in[10];
  const float* s_fc2_b    = (const float*)d_in[11];
  float* y = (float*)d_out;

  char* wsb = (char*)d_ws;
  int*   cnt      = (int*)(wsb + 0);
  int*   offs     = (int*)(wsb + 64);
  int*   topk_idx = (int*)(wsb + 256);
  float* topk_w   = (float*)(wsb + 24832);
  int*   row_tok  = (int*)(wsb + 49408);
  float* row_wt   = (float*)(wsb + 74496);
  int*   row_id   = (int*)(wsb + 99584);
  short* xbf      = (short*)(wsb + 131072);       // 2048x1024
  short* a_buf    = (short*)(wsb + 8519680);      // 6272x1024
  short* as_buf   = (short*)(wsb + 21364736);     // 2048x2048
  short* wbf_sfc1 = (short*)(wsb + 42598400);     // 4096x1024
  short* wbf_sfc2 = (short*)(wsb + 50987008);     // 1024x2048
  short* wbf_fc1  = (short*)(wsb + 55181312);     // 15x2048x1024
  short* wbf_fc2  = (short*)(wsb + 118095872);    // 15x1024x1024
  // total ~149.6 MB

  hipMemsetAsync(y, 0, (size_t)2048 * 1024 * 4, stream);  // y accumulated via atomics
  k_convert_w<<<6528, 256, 0, stream>>>(fc1_w, fc2_w, s_fc1_w, s_fc2_w,
                                        wbf_fc1, wbf_fc2, wbf_sfc1, wbf_sfc2);
  k_gate<<<512, 64, 0, stream>>>(x, gate_w, topk_idx, topk_w, xbf);
  k_route<<<1, 1024, 0, stream>>>(topk_idx, topk_w, cnt, offs, row_tok, row_wt, row_id);
  k_fc1<<<1520, 256, 0, stream>>>(xbf, wbf_sfc1, s_fc1_b, s_mult,
                                  wbf_fc1, fc1_b, geglu_mult,
                                  cnt, offs, row_tok, as_buf, a_buf);
  k_fc2<<<632, 256, 0, stream>>>(as_buf, wbf_sfc2, s_fc2_b,
                                 a_buf, wbf_fc2, fc2_b,
                                 cnt, offs, row_wt, row_tok, y);
}

// Round 6
// 476.213 us; speedup vs baseline: 1.0267x; 1.0267x over previous
//
#include <hip/hip_runtime.h>

typedef __attribute__((ext_vector_type(8))) short bfrag;
typedef __attribute__((ext_vector_type(4))) float f32x4;

__device__ __forceinline__ short f2bf(float f) {
  union { float f; unsigned u; } v; v.f = f;
  unsigned r = v.u + 0x7FFFu + ((v.u >> 16) & 1u);  // RNE
  return (short)(r >> 16);
}
__device__ __forceinline__ float bf2f(unsigned short h) {
  union { unsigned u; float f; } v; v.u = ((unsigned)h) << 16;
  return v.f;
}
__device__ __forceinline__ float gelu_exact(float g) {
  return 0.5f * g * (1.0f + erff(g * 0.70710678118654752f));
}
__device__ __forceinline__ void gld_lds16(const short* g, short* l) {
  __builtin_amdgcn_global_load_lds(
      (const __attribute__((address_space(1))) void*)g,
      (__attribute__((address_space(3))) void*)l, 16, 0, 0);
}

// ---------------- weights -> bf16: 8-deep load batches for MLP ----------------
__global__ __launch_bounds__(256) void k_convert_w(
    const float* __restrict__ s0, const float* __restrict__ s1,
    const float* __restrict__ s2, const float* __restrict__ s3,
    short* __restrict__ d0, short* __restrict__ d1,
    short* __restrict__ d2, short* __restrict__ d3)
{
  const int b = blockIdx.x;
  const float* s; short* d; long off;
  if (b < 3840)      { s = s0; d = d0; off = (long)b * 2048; }
  else if (b < 5760) { s = s1; d = d1; off = (long)(b - 3840) * 2048; }
  else if (b < 6272) { s = s2; d = d2; off = (long)(b - 5760) * 2048; }
  else               { s = s3; d = d3; off = (long)(b - 6272) * 2048; }
  const long base = off + threadIdx.x;
  float4 v[8];
#pragma unroll
  for (int j = 0; j < 8; j++) v[j] = ((const float4*)s)[base + j * 256];
#pragma unroll
  for (int j = 0; j < 8; j++)
    ((short4*)d)[base + j * 256] =
        make_short4(f2bf(v[j].x), f2bf(v[j].y), f2bf(v[j].z), f2bf(v[j].w));
}

// ---------------- gating (4 tokens/wave) + x->bf16 fused ----------------
__global__ __launch_bounds__(64) void k_gate(const float* __restrict__ x,
    const float* __restrict__ gw, int* __restrict__ topk_idx,
    float* __restrict__ topk_w, short* __restrict__ xbf)
{
  const int t0 = blockIdx.x * 4;
  const int lane = threadIdx.x;
  float xv[4][16];
#pragma unroll
  for (int tt = 0; tt < 4; tt++)
#pragma unroll
    for (int i = 0; i < 16; i++) {
      xv[tt][i] = x[(size_t)(t0 + tt) * 1024 + lane + 64 * i];
      xbf[(size_t)(t0 + tt) * 1024 + lane + 64 * i] = f2bf(xv[tt][i]);
    }
  float p[4][15];
#pragma unroll
  for (int e = 0; e < 15; e++) {
    float wv[16];
#pragma unroll
    for (int i = 0; i < 16; i++) wv[i] = gw[(size_t)e * 1024 + lane + 64 * i];
#pragma unroll
    for (int tt = 0; tt < 4; tt++) {
      float s = 0.f;
#pragma unroll
      for (int i = 0; i < 16; i++) s += xv[tt][i] * wv[i];
#pragma unroll
      for (int o = 32; o; o >>= 1) s += __shfl_xor(s, o, 64);
      p[tt][e] = s;
    }
  }
#pragma unroll
  for (int tt = 0; tt < 4; tt++) {
    float m = -1e30f;
#pragma unroll
    for (int e = 0; e < 15; e++) m = fmaxf(m, p[tt][e]);
    float q[15], Z = 0.f;
#pragma unroll
    for (int e = 0; e < 15; e++) { q[e] = expf(p[tt][e] - m); Z += q[e]; }
    int usedMask = 0; int bi[3]; float bv[3];
#pragma unroll
    for (int j = 0; j < 3; j++) {
      float best = -1.f; int b = 0;
#pragma unroll
      for (int e = 0; e < 15; e++) {
        bool ok = (!((usedMask >> e) & 1)) && (q[e] > best);
        if (ok) { best = q[e]; b = e; }
      }
      bi[j] = b; bv[j] = best / Z; usedMask |= 1 << b;
    }
    if (lane == tt) {
      float den = bv[0] + bv[1] + bv[2] + 1e-20f;
#pragma unroll
      for (int j = 0; j < 3; j++) {
        topk_idx[(t0 + tt) * 3 + j] = bi[j];
        topk_w[(t0 + tt) * 3 + j] = bv[j] / den;
      }
    }
  }
}

// ---------------- routing: single block, LDS atomics ----------------
__global__ __launch_bounds__(1024) void k_route(const int* __restrict__ topk_idx,
    const float* __restrict__ topk_w, int* __restrict__ cnt_g, int* __restrict__ offs_g,
    int* __restrict__ row_tok, float* __restrict__ row_wt, int* __restrict__ row_id)
{
  __shared__ int scnt[16], soffs[16], sfill[16];
  const int tid = threadIdx.x;
  if (tid < 16) { scnt[tid] = 0; sfill[tid] = 0; }
  __syncthreads();
  for (int i = tid; i < 6144; i += 1024) atomicAdd(&scnt[topk_idx[i]], 1);
  __syncthreads();
  if (tid == 0) {
    int a = 0;
    for (int e = 0; e < 15; e++) { soffs[e] = a; offs_g[e] = a; cnt_g[e] = scnt[e]; a += scnt[e]; }
  }
  __syncthreads();
  for (int i = tid; i < 6144; i += 1024) {
    int e = topk_idx[i];
    int pos = atomicAdd(&sfill[e], 1);
    int row = soffs[e] + pos;
    row_tok[row] = i / 3;
    row_wt[row] = topk_w[i];
    row_id[i] = row;
  }
}

__device__ __forceinline__ bool resolve_tile128(const int* __restrict__ cnt, int ty,
                                                int& e, int& lt) {
  int acc = 0;
#pragma unroll
  for (int i = 0; i < 15; i++) {
    int tl = (cnt[i] + 127) >> 7;
    if (ty < acc + tl) { e = i; lt = ty - acc; return true; }
    acc += tl;
  }
  return false;
}

// ============== unified fc1 (+geglu): shared blocks [0,512), expert [512,1520) ==============
__global__ __launch_bounds__(256) void k_fc1(
    const short* __restrict__ xbf,
    const short* __restrict__ wsh, const float* __restrict__ bsh, const float* __restrict__ msh,
    const short* __restrict__ wex, const float* __restrict__ bex, const float* __restrict__ mex,
    const int* __restrict__ cnt, const int* __restrict__ offs, const int* __restrict__ row_tok,
    short* __restrict__ as_buf, short* __restrict__ a_buf)
{
  __shared__ short smem[2 * 128 * 64];  // 32 KB
  short* As = smem;
  short* Bs = smem + 128 * 64;
  const int tid = threadIdx.x;
  const int bid = blockIdx.x;
  const bool sh = bid < 512;
  int f0, m0 = 0, e = 0, rowBase = 0, nrows = 128;
  if (sh) {
    f0 = (bid & 31) * 64; m0 = (bid >> 5) * 128;
  } else {
    const int b2 = bid - 512;
    int lt;
    if (!resolve_tile128(cnt, b2 >> 4, e, lt)) return;
    f0 = (b2 & 15) * 64;
    rowBase = offs[e] + lt * 128;
    nrows = cnt[e] - lt * 128; if (nrows > 128) nrows = 128;
  }
  const int lane = tid & 63, ml = lane & 15, kq = lane >> 4, mlo = lane & 7;
  const int wv = tid >> 6, wr = wv >> 1, wc = wv & 1;
  const int lrow = lane >> 3, lchk = lane & 7;
  const int Fhalf = sh ? 2048 : 1024;
  const short* wptr = sh ? wsh : (wex + (size_t)e * 2048 * 1024);
  const short* aSrc[4]; const short* bSrc[4];
#pragma unroll
  for (int t = 0; t < 4; t++) {
    const int r = wv * 32 + t * 8 + lrow;
    const int sc = (lchk ^ (r & 7)) * 8;
    if (sh) aSrc[t] = xbf + (size_t)(m0 + r) * 1024 + sc;
    else {
      const int rc = r < nrows ? r : nrows - 1;
      aSrc[t] = xbf + (size_t)row_tok[rowBase + rc] * 1024 + sc;
    }
    const int grow = (r < 64) ? (f0 + r) : (Fhalf + f0 + r - 64);
    bSrc[t] = wptr + (size_t)grow * 1024 + sc;
  }
  f32x4 acc[4][4] = {};
  for (int k0 = 0; k0 < 1024; k0 += 64) {
#pragma unroll
    for (int t = 0; t < 4; t++) gld_lds16(aSrc[t] + k0, As + (wv * 32 + t * 8) * 64);
#pragma unroll
    for (int t = 0; t < 4; t++) gld_lds16(bSrc[t] + k0, Bs + (wv * 32 + t * 8) * 64);
    __syncthreads();
#pragma unroll
    for (int kk = 0; kk < 2; kk++) {
      const int so = ((kk * 4 + kq) ^ mlo) * 8;
      bfrag af[4], bf[4];
#pragma unroll
      for (int i = 0; i < 4; i++) af[i] = *(bfrag*)&As[(wr * 64 + i * 16 + ml) * 64 + so];
#pragma unroll
      for (int j = 0; j < 4; j++) {
        const int brow = ((j >> 1) ? 64 : 0) + wc * 32 + (j & 1) * 16 + ml;
        bf[j] = *(bfrag*)&Bs[brow * 64 + so];
      }
#pragma unroll
      for (int i = 0; i < 4; i++)
#pragma unroll
        for (int j = 0; j < 4; j++)
          acc[i][j] = __builtin_amdgcn_mfma_f32_16x16x32_bf16(af[i], bf[j], acc[i][j], 0, 0, 0);
    }
    __syncthreads();
  }
  const float* bias = sh ? bsh : (bex + (size_t)e * 2048);
  const float* mult = sh ? msh : (mex + (size_t)e * 1024);
#pragma unroll
  for (int jj = 0; jj < 2; jj++) {
    const int fl = wc * 32 + jj * 16 + ml;
    const int f = f0 + fl;
    const float b1 = bias[f];
    const float b2 = bias[Fhalf + f];
    const float mv = mult[f];
#pragma unroll
    for (int i = 0; i < 4; i++)
#pragma unroll
      for (int rg = 0; rg < 4; rg++) {
        const int row = wr * 64 + i * 16 + kq * 4 + rg;
        const float h1 = acc[i][jj][rg] + b1;
        const float h2 = acc[i][jj + 2][rg] + b2;
        const short o = f2bf(gelu_exact(h2) * h1 * mv);
        if (sh) as_buf[(size_t)(m0 + row) * 2048 + f] = o;
        else if (row < nrows) a_buf[(size_t)(rowBase + row) * 1024 + f] = o;
      }
  }
}

// ============== unified fc2: shared blocks [0,128) write y; expert [128,632) write yexp ==============
__global__ __launch_bounds__(256) void k_fc2(
    const short* __restrict__ as_buf, const short* __restrict__ wsfc2, const float* __restrict__ s_b,
    const short* __restrict__ a_buf, const short* __restrict__ wfc2, const float* __restrict__ e_b,
    const int* __restrict__ cnt, const int* __restrict__ offs, const float* __restrict__ row_wt,
    float* __restrict__ y, short* __restrict__ yexp)
{
  __shared__ short smem[2 * 128 * 64];
  short* As = smem;
  short* Bs = smem + 128 * 64;
  const int tid = threadIdx.x;
  const int bid = blockIdx.x;
  const bool sh = bid < 128;
  int d0, m0 = 0, e = 0, rowBase = 0, nrows = 128, Klen, astr, bstr;
  const short *aBase, *bBase;
  if (sh) {
    d0 = (bid & 7) * 128; m0 = (bid >> 3) * 128;
    Klen = 2048; astr = 2048; bstr = 2048;
    aBase = as_buf; bBase = wsfc2;
  } else {
    const int b2 = bid - 128;
    int lt;
    if (!resolve_tile128(cnt, b2 >> 3, e, lt)) return;
    d0 = (b2 & 7) * 128;
    rowBase = offs[e] + lt * 128;
    nrows = cnt[e] - lt * 128; if (nrows > 128) nrows = 128;
    Klen = 1024; astr = 1024; bstr = 1024;
    aBase = a_buf + (size_t)rowBase * 1024;
    bBase = wfc2 + (size_t)e * 1024 * 1024;
  }
  const int lane = tid & 63, ml = lane & 15, kq = lane >> 4, mlo = lane & 7;
  const int wv = tid >> 6, wr = wv >> 1, wc = wv & 1;
  const int lrow = lane >> 3, lchk = lane & 7;
  const short* aSrc[4]; const short* bSrc[4];
#pragma unroll
  for (int t = 0; t < 4; t++) {
    const int r = wv * 32 + t * 8 + lrow;
    const int sc = (lchk ^ (r & 7)) * 8;
    aSrc[t] = aBase + (size_t)(sh ? (m0 + r) : r) * astr + sc;
    bSrc[t] = bBase + (size_t)(d0 + r) * bstr + sc;
  }
  f32x4 acc[4][4] = {};
  for (int k0 = 0; k0 < Klen; k0 += 64) {
#pragma unroll
    for (int t = 0; t < 4; t++) gld_lds16(aSrc[t] + k0, As + (wv * 32 + t * 8) * 64);
#pragma unroll
    for (int t = 0; t < 4; t++) gld_lds16(bSrc[t] + k0, Bs + (wv * 32 + t * 8) * 64);
    __syncthreads();
#pragma unroll
    for (int kk = 0; kk < 2; kk++) {
      const int so = ((kk * 4 + kq) ^ mlo) * 8;
      bfrag af[4], bf[4];
#pragma unroll
      for (int i = 0; i < 4; i++) af[i] = *(bfrag*)&As[(wr * 64 + i * 16 + ml) * 64 + so];
#pragma unroll
      for (int j = 0; j < 4; j++) bf[j] = *(bfrag*)&Bs[(wc * 64 + j * 16 + ml) * 64 + so];
#pragma unroll
      for (int i = 0; i < 4; i++)
#pragma unroll
        for (int j = 0; j < 4; j++)
          acc[i][j] = __builtin_amdgcn_mfma_f32_16x16x32_bf16(af[i], bf[j], acc[i][j], 0, 0, 0);
    }
    __syncthreads();
  }
#pragma unroll
  for (int j = 0; j < 4; j++) {
    const int d = d0 + wc * 64 + j * 16 + ml;
    const float bv = sh ? s_b[d] : e_b[(size_t)e * 1024 + d];
#pragma unroll
    for (int i = 0; i < 4; i++)
#pragma unroll
      for (int rg = 0; rg < 4; rg++) {
        const int row = wr * 64 + i * 16 + kq * 4 + rg;
        if (sh) {
          y[(size_t)(m0 + row) * 1024 + d] = acc[i][j][rg] + bv;
        } else if (row < nrows) {
          const float wt = row_wt[rowBase + row];
          yexp[(size_t)(rowBase + row) * 1024 + d] = f2bf((acc[i][j][rg] + bv) * wt);
        }
      }
  }
}

// ---------------- combine ----------------
__global__ __launch_bounds__(256) void k_combine(float* __restrict__ y,
    const short* __restrict__ yexp, const int* __restrict__ row_id)
{
  const int idx = blockIdx.x * 256 + threadIdx.x;
  const int t = idx >> 8;
  const int d4 = (idx & 255) * 4;
  const int r0 = row_id[t * 3], r1 = row_id[t * 3 + 1], r2 = row_id[t * 3 + 2];
  float4 acc = *(float4*)(y + (size_t)t * 1024 + d4);
  const ushort4 v0 = *(const ushort4*)(yexp + (size_t)r0 * 1024 + d4);
  const ushort4 v1 = *(const ushort4*)(yexp + (size_t)r1 * 1024 + d4);
  const ushort4 v2 = *(const ushort4*)(yexp + (size_t)r2 * 1024 + d4);
  acc.x += bf2f(v0.x) + bf2f(v1.x) + bf2f(v2.x);
  acc.y += bf2f(v0.y) + bf2f(v1.y) + bf2f(v2.y);
  acc.z += bf2f(v0.z) + bf2f(v1.z) + bf2f(v2.z);
  acc.w += bf2f(v0.w) + bf2f(v1.w) + bf2f(v2.w);
  *(float4*)(y + (size_t)t * 1024 + d4) = acc;
}

extern "C" void kernel_launch(void* const* d_in, const int* in_sizes, int n_in,
                              void* d_out, int out_size, void* d_ws, size_t ws_size,
                              hipStream_t stream) {
  const float* x          = (const float*)d_in[0];
  const float* gate_w     = (const float*)d_in[1];
  const float* fc1_w      = (const float*)d_in[2];
  const float* fc1_b      = (const float*)d_in[3];
  const float* geglu_mult = (const float*)d_in[4];
  const float* fc2_w      = (const float*)d_in[5];
  const float* fc2_b      = (const float*)d_in[6];
  const float* s_fc1_w    = (const float*)d_in[7];
  const float* s_fc1_b    = (const float*)d_in[8];
  const float* s_mult     = (const float*)d_in[9];
  const float* s_fc2_w    = (const float*)d_in[10];
  const float* s_fc2_b    = (const float*)d_in[11];
  float* y = (float*)d_out;

  char* wsb = (char*)d_ws;
  int*   cnt      = (int*)(wsb + 0);
  int*   offs     = (int*)(wsb + 64);
  int*   topk_idx = (int*)(wsb + 256);
  float* topk_w   = (float*)(wsb + 24832);
  int*   row_tok  = (int*)(wsb + 49408);
  float* row_wt   = (float*)(wsb + 74496);
  int*   row_id   = (int*)(wsb + 99584);
  short* xbf      = (short*)(wsb + 131072);       // 2048x1024
  short* a_buf    = (short*)(wsb + 8519680);      // 6272x1024
  short* as_buf   = (short*)(wsb + 21364736);     // 2048x2048
  short* yexp     = (short*)(wsb + 29753344);     // 6272x1024
  short* wbf_sfc1 = (short*)(wsb + 42598400);     // 4096x1024
  short* wbf_sfc2 = (short*)(wsb + 50987008);     // 1024x2048
  short* wbf_fc1  = (short*)(wsb + 55181312);     // 15x2048x1024
  short* wbf_fc2  = (short*)(wsb + 118095872);    // 15x1024x1024
  // total ~149.6 MB

  k_convert_w<<<6528, 256, 0, stream>>>(fc1_w, fc2_w, s_fc1_w, s_fc2_w,
                                        wbf_fc1, wbf_fc2, wbf_sfc1, wbf_sfc2);
  k_gate<<<512, 64, 0, stream>>>(x, gate_w, topk_idx, topk_w, xbf);
  k_route<<<1, 1024, 0, stream>>>(topk_idx, topk_w, cnt, offs, row_tok, row_wt, row_id);
  k_fc1<<<1520, 256, 0, stream>>>(xbf, wbf_sfc1, s_fc1_b, s_mult,
                                  wbf_fc1, fc1_b, geglu_mult,
                                  cnt, offs, row_tok, as_buf, a_buf);
  k_fc2<<<632, 256, 0, stream>>>(as_buf, wbf_sfc2, s_fc2_b,
                                 a_buf, wbf_fc2, fc2_b,
                                 cnt, offs, row_wt, y, yexp);
  k_combine<<<2048, 256, 0, stream>>>(y, yexp, row_id);
}